// Round 8
// baseline (118.735 us; speedup 1.0000x reference)
//
#include <hip/hip_runtime.h>
#include <hip/hip_bf16.h>
#include <hip/hip_fp16.h>

#define B_ 2
#define C_ 64
#define H_ 192
#define W_ 384
#define K_ 8
constexpr int HW_ = H_ * W_;
constexpr int CHW_ = C_ * HW_;
constexpr int NP_ = B_ * HW_;           // 147456
constexpr int NBLK_ = NP_ / 64;         // 2304, %8==0
constexpr size_t WS_NEED_ = (size_t)NP_ * 64 * sizeof(unsigned short);  // 18.9 MB bf16 NHWC

// =================== K1: NCHW fp32 -> NHWC bf16 transpose ===================
__global__ __launch_bounds__(256) void transpose16_kernel(
    const float* __restrict__ feat, unsigned short* __restrict__ ft) {
  __shared__ float lds[64 * 65];
  const int tid = threadIdx.x;
  const int lane = tid & 63;
  const int wv = tid >> 6;
  const int p0 = blockIdx.x * 64;
  const int b = p0 / HW_;
  const int hw0 = p0 - b * HW_;
  const float* fb = feat + (size_t)b * CHW_;
#pragma unroll
  for (int cc = 0; cc < 16; ++cc) {
    const int c = wv * 16 + cc;
    lds[lane * 65 + c] = fb[(size_t)c * HW_ + hw0 + lane];   // coalesced 256B
  }
  __syncthreads();
  uint* ft32 = (uint*)ft;
#pragma unroll
  for (int j = 0; j < 8; ++j) {
    const int idx = j * 256 + tid;       // uint index within block tile
    const int row = idx >> 5;            // pixel 0..63
    const int cp = idx & 31;             // channel pair
    __hip_bfloat16 h0 = __float2bfloat16(lds[row * 65 + 2 * cp]);
    __hip_bfloat16 h1 = __float2bfloat16(lds[row * 65 + 2 * cp + 1]);
    const uint u = (uint)*(unsigned short*)&h0 | ((uint)*(unsigned short*)&h1 << 16);
    ft32[(size_t)(p0 + row) * 32 + cp] = u;
  }
}

// =================== K2: conv + softmax + compacted gather + epilogue ===================
// block = 256 thr = 4 waves, 64 pixels. LDS (4B units, total 6784 = 27136 B):
//  era1: A0=[0,1536) w0 partials [24][64]; A1=[1536,3072) w1. w2/w3 fold in place.
//  era2: triples [0,1536): tpx[k][px], tpy(+512), tw(+1024)  (w0 writes)
//  era2: reco uint4[8][64] @ [1536,3584); recw uint2[8][64] @ [3584,4608)
//  persistent: resb uint[64][33] @ [4608,6720); actl @ [6720,6784)
__global__ __launch_bounds__(256, 5) void fusedg_kernel(
    const float* __restrict__ feat, const int* __restrict__ mask,
    const float* __restrict__ Wo, const float* __restrict__ bo,
    const float* __restrict__ Ww, const float* __restrict__ bw,
    const unsigned short* __restrict__ ws, float* __restrict__ out) {
  __shared__ uint smem[6784];
  float* f32 = (float*)smem;
  uint4* reco = (uint4*)(smem + 1536);
  uint2* recw = (uint2*)(smem + 3584);
  uint* resb = smem + 4608;
  int* actl = (int*)(smem + 6720);

  const int tid = threadIdx.x;
  const int lane = tid & 63;
  const int wv = tid >> 6;
  const int bid = blockIdx.x;
  const int sb = (bid & 7) * (NBLK_ / 8) + (bid >> 3);   // bijective XCD swizzle
  const int p0 = sb * 64;
  const int b = p0 / HW_;
  const int hw0 = p0 - b * HW_;
  const size_t bCHW = (size_t)b * CHW_;
  const float* fb = feat + bCHW;
  const int bHW = b * HW_;

  // ---- phase A: conv partials (wave = 16 channels, lane = pixel) ----
  float pacc[24];
#pragma unroll
  for (int j = 0; j < 24; ++j) pacc[j] = 0.f;
#pragma unroll
  for (int cc = 0; cc < 16; ++cc) {
    const int c = wv * 16 + cc;                       // wave-uniform -> s_load weights
    const float v = fb[(size_t)c * HW_ + hw0 + lane]; // coalesced
#pragma unroll
    for (int j = 0; j < 16; ++j) pacc[j] = fmaf(Wo[j * C_ + c], v, pacc[j]);
#pragma unroll
    for (int j = 0; j < 8; ++j) pacc[16 + j] = fmaf(Ww[j * C_ + c], v, pacc[16 + j]);
  }
  if (wv < 2) {
#pragma unroll
    for (int j = 0; j < 24; ++j) f32[wv * 1536 + j * 64 + lane] = pacc[j];
  }
  __syncthreads();   // b1
  if (wv >= 2) {     // fold in place: B = A0 + w2, C = A1 + w3
    const int base = (wv - 2) * 1536;
#pragma unroll
    for (int j = 0; j < 24; ++j)
      f32[base + j * 64 + lane] += pacc[j];
  } else {
    // zero resb in parallel with fold (region disjoint from A0/A1)
    for (int j = 0; j < 17; ++j) {
      const int idx = j * 128 + (wv * 64 + lane);
      if (idx < 2112) resb[idx] = 0u;
    }
  }

  // mask + ballot: every wave computes identically (needs only mask)
  const bool act = (mask[p0 + lane] != 0);
  const unsigned long long mball = __ballot(act);
  const int A = __popcll(mball);
  __syncthreads();   // b2: B,C final; resb zeroed

  // ---- phase B (wave 0 only): final reduce + softmax + triples + actl ----
  if (wv == 0) {
    float acc[24];
#pragma unroll
    for (int j = 0; j < 24; ++j)
      acc[j] = f32[j * 64 + lane] + f32[1536 + j * 64 + lane];
#pragma unroll
    for (int j = 0; j < 16; ++j) acc[j] += bo[j];
#pragma unroll
    for (int j = 0; j < 8; ++j) acc[16 + j] += bw[j];
    float m = acc[16];
#pragma unroll
    for (int k = 1; k < K_; ++k) m = fmaxf(m, acc[16 + k]);
    float s = 0.f;
#pragma unroll
    for (int k = 0; k < K_; ++k) s += __expf(acc[16 + k] - m);
    const float inv = (act ? 1.f : 0.f) / s;
    const int hw = hw0 + lane;
    const int y = hw / W_;
    const int x = hw - y * W_;
    // in-wave ordering: all B/C reads above precede these overwrites (same region)
#pragma unroll
    for (int k = 0; k < K_; ++k) {
      f32[k * 64 + lane] = (float)x + acc[2 * k];
      f32[512 + k * 64 + lane] = (float)y + acc[2 * k + 1];
      f32[1024 + k * 64 + lane] = __expf(acc[16 + k] - m) * inv;
    }
    // active-pixel compaction
    const int aidx = __builtin_amdgcn_mbcnt_hi(
        (unsigned)(mball >> 32), __builtin_amdgcn_mbcnt_lo((unsigned)mball, 0));
    if (act) actl[aidx] = lane;
    if (A > 0) {
      const int first = __ffsll((unsigned long long)mball) - 1;
      if (lane >= A) actl[lane] = first;   // sentinel pad
    }
  }
  __syncthreads();   // b3: triples + actl ready

  // ---- record expansion: ALL lanes. lane = (pxl16, kq4); 2 k's each ----
  {
    const int pxl = wv * 16 + (lane & 15);
    const int kq = lane >> 4;
    const bool pact = ((mball >> pxl) & 1ull) != 0;
    const int hw_e = hw0 + pxl;
    (void)hw_e;
#pragma unroll
    for (int t = 0; t < 2; ++t) {
      const int k = kq * 2 + t;
      const float px = f32[k * 64 + pxl];
      const float py = f32[512 + k * 64 + pxl];
      const float wtk = f32[1024 + k * 64 + pxl];
      const float x0f = floorf(px), y0f = floorf(py);
      const float wx = px - x0f, wy = py - y0f;
      const int x0 = (int)x0f, y0 = (int)y0f;
      const int x1 = x0 + 1, y1 = y0 + 1;
      const bool vx0 = ((unsigned)x0 < (unsigned)W_);
      const bool vx1 = ((unsigned)x1 < (unsigned)W_);
      const bool vy0 = ((unsigned)y0 < (unsigned)H_);
      const bool vy1 = ((unsigned)y1 < (unsigned)H_);
      const int cx0 = min(max(x0, 0), W_ - 1), cx1 = min(max(x1, 0), W_ - 1);
      const int cy0 = min(max(y0, 0), H_ - 1), cy1 = min(max(y1, 0), H_ - 1);
      const float w00 = wtk * (1.f - wx) * (1.f - wy) * ((vx0 && vy0) ? 1.f : 0.f);
      const float w01 = wtk * wx * (1.f - wy) * ((vx1 && vy0) ? 1.f : 0.f);
      const float w10 = wtk * (1.f - wx) * wy * ((vx0 && vy1) ? 1.f : 0.f);
      const float w11 = wtk * wx * wy * ((vx1 && vy1) ? 1.f : 0.f);
      uint4 o;
      o.x = pact ? (uint)((bHW + cy0 * W_ + cx0) << 7) : 0u;
      o.y = pact ? (uint)((bHW + cy0 * W_ + cx1) << 7) : 0u;
      o.z = pact ? (uint)((bHW + cy1 * W_ + cx0) << 7) : 0u;
      o.w = pact ? (uint)((bHW + cy1 * W_ + cx1) << 7) : 0u;
      __half2 h01 = __floats2half2_rn(w00, w01);
      __half2 h23 = __floats2half2_rn(w10, w11);
      uint2 wp;
      wp.x = *(uint*)&h01;
      wp.y = *(uint*)&h23;
      reco[k * 64 + pxl] = o;
      recw[k * 64 + pxl] = wp;
    }
  }
  __syncthreads();   // b4: records ready

  // ---- phase C: compacted gather. lane = (pg8, cg8 of 8 bf16 ch) ----
  const int pg = lane >> 3;
  const int cg = lane & 7;
  const int cgb = cg * 16;             // byte offset within 128B row
  const char* ftb = (const char*)ws;
  const int tot = (A + 7) >> 3;

#define ACC8(V, WT)                                                        \
  do {                                                                     \
    rr[0] = fmaf(WT, __uint_as_float((V).x << 16), rr[0]);                 \
    rr[1] = fmaf(WT, __uint_as_float((V).x & 0xffff0000u), rr[1]);         \
    rr[2] = fmaf(WT, __uint_as_float((V).y << 16), rr[2]);                 \
    rr[3] = fmaf(WT, __uint_as_float((V).y & 0xffff0000u), rr[3]);         \
    rr[4] = fmaf(WT, __uint_as_float((V).z << 16), rr[4]);                 \
    rr[5] = fmaf(WT, __uint_as_float((V).z & 0xffff0000u), rr[5]);         \
    rr[6] = fmaf(WT, __uint_as_float((V).w << 16), rr[6]);                 \
    rr[7] = fmaf(WT, __uint_as_float((V).w & 0xffff0000u), rr[7]);         \
  } while (0)

  for (int i = wv; i < tot; i += 4) {
    const int gi = i * 8 + pg;
    const int pxl = actl[gi];
    float rr[8];
#pragma unroll
    for (int j = 0; j < 8; ++j) rr[j] = 0.f;
#pragma unroll
    for (int k2 = 0; k2 < 4; ++k2) {
      const int k0 = 2 * k2, k1 = 2 * k2 + 1;
      const uint4 o0 = reco[k0 * 64 + pxl];
      const uint2 wp0 = recw[k0 * 64 + pxl];
      const uint4 o1 = reco[k1 * 64 + pxl];
      const uint2 wp1 = recw[k1 * 64 + pxl];
      const uint4 v0 = *(const uint4*)(ftb + (o0.x + cgb));
      const uint4 v1 = *(const uint4*)(ftb + (o0.y + cgb));
      const uint4 v2 = *(const uint4*)(ftb + (o0.z + cgb));
      const uint4 v3 = *(const uint4*)(ftb + (o0.w + cgb));
      const uint4 v4 = *(const uint4*)(ftb + (o1.x + cgb));
      const uint4 v5 = *(const uint4*)(ftb + (o1.y + cgb));
      const uint4 v6 = *(const uint4*)(ftb + (o1.z + cgb));
      const uint4 v7 = *(const uint4*)(ftb + (o1.w + cgb));
      const float2 wa0 = __half22float2(*(const __half2*)&wp0.x);
      const float2 wb0 = __half22float2(*(const __half2*)&wp0.y);
      const float2 wa1 = __half22float2(*(const __half2*)&wp1.x);
      const float2 wb1 = __half22float2(*(const __half2*)&wp1.y);
      ACC8(v0, wa0.x); ACC8(v1, wa0.y); ACC8(v2, wb0.x); ACC8(v3, wb0.y);
      ACC8(v4, wa1.x); ACC8(v5, wa1.y); ACC8(v6, wb1.x); ACC8(v7, wb1.y);
    }
    if (gi < A) {
      const int base = pxl * 33 + cg * 4;
#pragma unroll
      for (int j = 0; j < 4; ++j) {
        __hip_bfloat16 l = __float2bfloat16(rr[2 * j]);
        __hip_bfloat16 h = __float2bfloat16(rr[2 * j + 1]);
        resb[base + j] =
            (uint)*(unsigned short*)&l | ((uint)*(unsigned short*)&h << 16);
      }
    }
  }
#undef ACC8
  __syncthreads();   // b5: res ready

  // ---- phase D: epilogue, coalesced NCHW (feat re-read; L2/L3-hot) ----
#pragma unroll
  for (int cc8 = 0; cc8 < 8; ++cc8) {
    const int c = wv * 16 + cc8 * 2;
    const int cp = (c >> 1);
    const uint u = resb[lane * 33 + cp];
    const float r0 = __uint_as_float(u << 16);
    const float r1 = __uint_as_float(u & 0xffff0000u);
    const size_t off = bCHW + (size_t)c * HW_ + hw0 + lane;
    out[off] = feat[off] + r0;
    out[off + HW_] = feat[off + HW_] + r1;
  }
}

// =================== Fallback (ws-free, round-1 fused) ===================
__global__ __launch_bounds__(256) void fused_kernel(
    const float* __restrict__ feat, const int* __restrict__ mask,
    const float* __restrict__ Wo, const float* __restrict__ bo,
    const float* __restrict__ Ww, const float* __restrict__ bw,
    float* __restrict__ out) {
  const int p = blockIdx.x * blockDim.x + threadIdx.x;
  const int b = p / HW_;
  const int hw = p - b * HW_;
  const int y = hw / W_;
  const int x = hw - y * W_;
  const float* fb = feat + b * CHW_;
  float acc[24];
#pragma unroll
  for (int i = 0; i < 16; ++i) acc[i] = bo[i];
#pragma unroll
  for (int i = 0; i < 8; ++i) acc[16 + i] = bw[i];
#pragma unroll
  for (int c = 0; c < C_; ++c) {
    const float v = fb[c * HW_ + hw];
#pragma unroll
    for (int i = 0; i < 16; ++i) acc[i] = fmaf(Wo[i * C_ + c], v, acc[i]);
#pragma unroll
    for (int i = 0; i < 8; ++i) acc[16 + i] = fmaf(Ww[i * C_ + c], v, acc[16 + i]);
  }
  float m = acc[16];
#pragma unroll
  for (int k = 1; k < K_; ++k) m = fmaxf(m, acc[16 + k]);
  float wt[K_];
  float s = 0.f;
#pragma unroll
  for (int k = 0; k < K_; ++k) { wt[k] = __expf(acc[16 + k] - m); s += wt[k]; }
  const float fm = (mask[p] != 0) ? 1.f : 0.f;
  const float inv = fm / s;
#pragma unroll
  for (int k = 0; k < K_; ++k) wt[k] *= inv;
  float res[C_];
#pragma unroll
  for (int c = 0; c < C_; ++c) res[c] = 0.f;
  if (fm != 0.f) {
#pragma unroll
    for (int k = 0; k < K_; ++k) {
      const float px = (float)x + acc[2 * k];
      const float py = (float)y + acc[2 * k + 1];
      const float x0f = floorf(px), y0f = floorf(py);
      const float wx = px - x0f, wy = py - y0f;
      const int x0 = (int)x0f, y0 = (int)y0f;
      const int x1 = x0 + 1, y1 = y0 + 1;
      const bool vx0 = ((unsigned)x0 < (unsigned)W_);
      const bool vx1 = ((unsigned)x1 < (unsigned)W_);
      const bool vy0 = ((unsigned)y0 < (unsigned)H_);
      const bool vy1 = ((unsigned)y1 < (unsigned)H_);
      const int cx0 = min(max(x0, 0), W_ - 1), cx1 = min(max(x1, 0), W_ - 1);
      const int cy0 = min(max(y0, 0), H_ - 1), cy1 = min(max(y1, 0), H_ - 1);
      const float wk = wt[k];
      const float w00 = wk * (1.f - wx) * (1.f - wy) * ((vx0 && vy0) ? 1.f : 0.f);
      const float w01 = wk * wx * (1.f - wy) * ((vx1 && vy0) ? 1.f : 0.f);
      const float w10 = wk * (1.f - wx) * wy * ((vx0 && vy1) ? 1.f : 0.f);
      const float w11 = wk * wx * wy * ((vx1 && vy1) ? 1.f : 0.f);
      const int i00 = cy0 * W_ + cx0, i01 = cy0 * W_ + cx1;
      const int i10 = cy1 * W_ + cx0, i11 = cy1 * W_ + cx1;
#pragma unroll
      for (int c = 0; c < C_; ++c) {
        const float* fc = fb + c * HW_;
        res[c] += w00 * fc[i00] + w01 * fc[i01] + w10 * fc[i10] + w11 * fc[i11];
      }
    }
  }
#pragma unroll
  for (int c = 0; c < C_; ++c)
    out[b * CHW_ + c * HW_ + hw] = fb[c * HW_ + hw] + res[c];
}

extern "C" void kernel_launch(void* const* d_in, const int* in_sizes, int n_in,
                              void* d_out, int out_size, void* d_ws, size_t ws_size,
                              hipStream_t stream) {
  const float* feat = (const float*)d_in[0];
  const int* mask = (const int*)d_in[1];
  const float* Wo = (const float*)d_in[2];
  const float* bo = (const float*)d_in[3];
  const float* Ww = (const float*)d_in[4];
  const float* bw = (const float*)d_in[5];
  float* out = (float*)d_out;

  if (ws_size >= WS_NEED_) {
    unsigned short* ws = (unsigned short*)d_ws;
    hipLaunchKernelGGL(transpose16_kernel, dim3(NBLK_), dim3(256), 0, stream,
                       feat, ws);
    hipLaunchKernelGGL(fusedg_kernel, dim3(NBLK_), dim3(256), 0, stream,
                       feat, mask, Wo, bo, Ww, bw, ws, out);
  } else {
    hipLaunchKernelGGL(fused_kernel, dim3(NP_ / 256), dim3(256), 0, stream,
                       feat, mask, Wo, bo, Ww, bw, out);
  }
}

// Round 9
// 58.033 us; speedup vs baseline: 2.0460x; 2.0460x over previous
//
#include <hip/hip_runtime.h>
#include <hip/hip_fp16.h>

#define B_ 2
#define C_ 64
#define H_ 192
#define W_ 384
#define K_ 8
constexpr int HW_ = H_ * W_;
constexpr int CHW_ = C_ * HW_;
constexpr int NP_ = B_ * HW_;           // 147456
constexpr int NBLK_ = NP_ / 64;         // 2304, %8==0
constexpr size_t WS_NEED_ = (size_t)NP_ * 64 * sizeof(unsigned short);  // 18.9 MB fp16 NHWC

static __device__ __forceinline__ __half2 u2h(uint u) {
  union { uint u; __half2 h; } x; x.u = u; return x.h;
}
static __device__ __forceinline__ uint h2u(__half2 h) {
  union { uint u; __half2 h; } x; x.h = h; return x.u;
}

// =================== K1: NCHW fp32 -> NHWC fp16 transpose ===================
__global__ __launch_bounds__(256) void transposeh_kernel(
    const float* __restrict__ feat, unsigned short* __restrict__ ft) {
  __shared__ float lds[64 * 65];
  const int tid = threadIdx.x;
  const int lane = tid & 63;
  const int wv = tid >> 6;
  const int p0 = blockIdx.x * 64;
  const int b = p0 / HW_;
  const int hw0 = p0 - b * HW_;
  const float* fb = feat + (size_t)b * CHW_;
#pragma unroll
  for (int cc = 0; cc < 16; ++cc) {
    const int c = wv * 16 + cc;
    lds[lane * 65 + c] = fb[(size_t)c * HW_ + hw0 + lane];   // coalesced 256B
  }
  __syncthreads();
  uint* ft32 = (uint*)ft;
#pragma unroll
  for (int j = 0; j < 8; ++j) {
    const int idx = j * 256 + tid;       // uint index within block tile
    const int row = idx >> 5;            // pixel 0..63
    const int cp = idx & 31;             // channel pair
    const __half2 h = __floats2half2_rn(lds[row * 65 + 2 * cp],
                                        lds[row * 65 + 2 * cp + 1]);
    ft32[(size_t)(p0 + row) * 32 + cp] = h2u(h);
  }
}

// =================== K2: conv + softmax + compacted gather + epilogue ===================
// block = 256 thr = 4 waves, 64 pixels. LDS (uints, total 6272 = 25088 B):
//  conv era: f32 partials [24][4][64] @ [0,6144)
//  rec era (after b2): reco uint4[8][64] @ [0,2048); recw uint4[8][64] @ [2048,4096)
//  resb half2[64][33] @ [4096,6208)  (zeroed after b2; conv region dead)
//  actl @ [6208,6272)
__global__ __launch_bounds__(256) void fusedg_kernel(
    const float* __restrict__ feat, const int* __restrict__ mask,
    const float* __restrict__ Wo, const float* __restrict__ bo,
    const float* __restrict__ Ww, const float* __restrict__ bw,
    const unsigned short* __restrict__ ws, float* __restrict__ out) {
  __shared__ uint smem[6272];
  float* f32 = (float*)smem;
  uint4* reco = (uint4*)smem;
  uint4* recw = (uint4*)(smem + 2048);
  uint* resb = smem + 4096;
  int* actl = (int*)(smem + 6208);

  const int tid = threadIdx.x;
  const int lane = tid & 63;
  const int wv = tid >> 6;
  const int bid = blockIdx.x;
  const int sb = (bid & 7) * (NBLK_ / 8) + (bid >> 3);   // bijective XCD swizzle
  const int p0 = sb * 64;
  const int b = p0 / HW_;
  const int hw0 = p0 - b * HW_;
  const size_t bCHW = (size_t)b * CHW_;
  const float* fb = feat + bCHW;
  const int bHW = b * HW_;

  // ---- phase A: conv partials (wave = 16 channels, lane = pixel) ----
  float pacc[24];
#pragma unroll
  for (int j = 0; j < 24; ++j) pacc[j] = 0.f;
#pragma unroll
  for (int cc = 0; cc < 16; ++cc) {
    const int c = wv * 16 + cc;                       // wave-uniform -> s_load weights
    const float v = fb[(size_t)c * HW_ + hw0 + lane]; // coalesced
#pragma unroll
    for (int j = 0; j < 16; ++j) pacc[j] = fmaf(Wo[j * C_ + c], v, pacc[j]);
#pragma unroll
    for (int j = 0; j < 8; ++j) pacc[16 + j] = fmaf(Ww[j * C_ + c], v, pacc[16 + j]);
  }
#pragma unroll
  for (int j = 0; j < 24; ++j) f32[j * 256 + wv * 64 + lane] = pacc[j];
  __syncthreads();   // b1

  // ---- phase B: cross-wave reduce (every wave, lane = pixel) ----
  float acc[24];
#pragma unroll
  for (int j = 0; j < 24; ++j)
    acc[j] = (f32[j * 256 + lane] + f32[j * 256 + 64 + lane]) +
             (f32[j * 256 + 128 + lane] + f32[j * 256 + 192 + lane]);
  __syncthreads();   // b2: conv region dead

#pragma unroll
  for (int j = 0; j < 16; ++j) acc[j] += bo[j];
#pragma unroll
  for (int j = 0; j < 8; ++j) acc[16 + j] += bw[j];

  // softmax + mask fold (lane = pixel)
  float m = acc[16];
#pragma unroll
  for (int k = 1; k < K_; ++k) m = fmaxf(m, acc[16 + k]);
  float s = 0.f;
#pragma unroll
  for (int k = 0; k < K_; ++k) s += __expf(acc[16 + k] - m);
  const bool act = (mask[p0 + lane] != 0);
  const float inv = (act ? 1.f : 0.f) / s;

  // active-pixel compaction (identical across all 4 waves: lane = pixel)
  const unsigned long long mball = __ballot(act);
  const int A = __popcll(mball);
  const int aidx = __builtin_amdgcn_mbcnt_hi(
      (unsigned)(mball >> 32), __builtin_amdgcn_mbcnt_lo((unsigned)mball, 0));
  if (act) actl[aidx] = lane;                       // all waves write same values
  if (A > 0) {
    const int first = __ffsll((unsigned long long)mball) - 1;
    if (lane >= A) actl[lane] = first;              // sentinel pad (loads only)
  }

  const int hw = hw0 + lane;
  const int y = hw / W_;
  const int x = hw - y * W_;

  // records for this wave's 16 pixels (lanes 16wv..16wv+15 own pixel = lane)
  if ((lane >> 4) == wv) {
    const int pxl = lane;
#pragma unroll
    for (int k = 0; k < K_; ++k) {
      const float wtk = __expf(acc[16 + k] - m) * inv;
      const float px = (float)x + acc[2 * k];
      const float py = (float)y + acc[2 * k + 1];
      const float x0f = floorf(px), y0f = floorf(py);
      const float wx = px - x0f, wy = py - y0f;
      const int x0 = (int)x0f, y0 = (int)y0f;
      const int x1 = x0 + 1, y1 = y0 + 1;
      const bool vx0 = ((unsigned)x0 < (unsigned)W_);
      const bool vx1 = ((unsigned)x1 < (unsigned)W_);
      const bool vy0 = ((unsigned)y0 < (unsigned)H_);
      const bool vy1 = ((unsigned)y1 < (unsigned)H_);
      const int cx0 = min(max(x0, 0), W_ - 1), cx1 = min(max(x1, 0), W_ - 1);
      const int cy0 = min(max(y0, 0), H_ - 1), cy1 = min(max(y1, 0), H_ - 1);
      const float w00 = wtk * (1.f - wx) * (1.f - wy) * ((vx0 && vy0) ? 1.f : 0.f);
      const float w01 = wtk * wx * (1.f - wy) * ((vx1 && vy0) ? 1.f : 0.f);
      const float w10 = wtk * (1.f - wx) * wy * ((vx0 && vy1) ? 1.f : 0.f);
      const float w11 = wtk * wx * wy * ((vx1 && vy1) ? 1.f : 0.f);
      // byte offsets into fp16 NHWC (128B rows); masked -> offset 0, w=0
      uint4 o;
      o.x = act ? (uint)((bHW + cy0 * W_ + cx0) << 7) : 0u;
      o.y = act ? (uint)((bHW + cy0 * W_ + cx1) << 7) : 0u;
      o.z = act ? (uint)((bHW + cy1 * W_ + cx0) << 7) : 0u;
      o.w = act ? (uint)((bHW + cy1 * W_ + cx1) << 7) : 0u;
      uint4 wq;
      wq.x = h2u(__float2half2_rn(w00));   // (w,w) duplicated for pk_fma
      wq.y = h2u(__float2half2_rn(w01));
      wq.z = h2u(__float2half2_rn(w10));
      wq.w = h2u(__float2half2_rn(w11));
      reco[k * 64 + pxl] = o;
      recw[k * 64 + pxl] = wq;
    }
  }

  // zero res rows (masked pixels keep zeros; active rows overwritten below)
#pragma unroll
  for (int j = 0; j < 9; ++j) {
    const int idx = j * 256 + tid;
    if (idx < 2112) resb[idx] = 0u;
  }
  __syncthreads();   // b3: records + actlist + zeros visible

  // ---- phase C: compacted gather. lane = (pg8, cg8 of 8 fp16 ch) ----
  const int pg = lane >> 3;
  const int cg = lane & 7;
  const int cgb = cg * 16;             // byte offset within 128B row
  const char* ftb = (const char*)ws;
  const int tot = (A + 7) >> 3;

#define ACCH(V, WU)                                                        \
  do {                                                                     \
    const __half2 wh_ = u2h(WU);                                           \
    rr0 = __hfma2(wh_, u2h((V).x), rr0);                                   \
    rr1 = __hfma2(wh_, u2h((V).y), rr1);                                   \
    rr2 = __hfma2(wh_, u2h((V).z), rr2);                                   \
    rr3 = __hfma2(wh_, u2h((V).w), rr3);                                   \
  } while (0)

  for (int i = wv; i < tot; i += 4) {   // round-robin passes across waves
    const int gi = i * 8 + pg;
    const int pxl = actl[gi];           // sentinel-padded
    __half2 rr0 = __float2half2_rn(0.f), rr1 = rr0, rr2 = rr0, rr3 = rr0;
#pragma unroll
    for (int k2 = 0; k2 < 4; ++k2) {    // k pair: 8 staged loads in flight
      const int k0 = 2 * k2, k1 = 2 * k2 + 1;
      const uint4 o0 = reco[k0 * 64 + pxl];
      const uint4 w0 = recw[k0 * 64 + pxl];
      const uint4 o1 = reco[k1 * 64 + pxl];
      const uint4 w1 = recw[k1 * 64 + pxl];
      const uint4 v0 = *(const uint4*)(ftb + (o0.x + cgb));
      const uint4 v1 = *(const uint4*)(ftb + (o0.y + cgb));
      const uint4 v2 = *(const uint4*)(ftb + (o0.z + cgb));
      const uint4 v3 = *(const uint4*)(ftb + (o0.w + cgb));
      const uint4 v4 = *(const uint4*)(ftb + (o1.x + cgb));
      const uint4 v5 = *(const uint4*)(ftb + (o1.y + cgb));
      const uint4 v6 = *(const uint4*)(ftb + (o1.z + cgb));
      const uint4 v7 = *(const uint4*)(ftb + (o1.w + cgb));
      ACCH(v0, w0.x); ACCH(v1, w0.y); ACCH(v2, w0.z); ACCH(v3, w0.w);
      ACCH(v4, w1.x); ACCH(v5, w1.y); ACCH(v6, w1.z); ACCH(v7, w1.w);
    }
    if (gi < A) {                       // sentinel passes don't write
      const int base = pxl * 33 + cg * 4;
      resb[base + 0] = h2u(rr0);
      resb[base + 1] = h2u(rr1);
      resb[base + 2] = h2u(rr2);
      resb[base + 3] = h2u(rr3);
    }
  }
#undef ACCH
  __syncthreads();   // b4: res ready

  // ---- phase D: epilogue, coalesced NCHW (feat re-read; L2-hot) ----
#pragma unroll
  for (int cc = 0; cc < 8; ++cc) {
    const int cp = wv * 8 + cc;               // channel pair {2cp, 2cp+1}
    const float2 f = __half22float2(u2h(resb[lane * 33 + cp]));
    const size_t off = bCHW + (size_t)(2 * cp) * HW_ + hw0 + lane;
    out[off] = feat[off] + f.x;
    out[off + HW_] = feat[off + HW_] + f.y;
  }
}

// =================== Fallback (ws-free, round-1 fused) ===================
__global__ __launch_bounds__(256) void fused_kernel(
    const float* __restrict__ feat, const int* __restrict__ mask,
    const float* __restrict__ Wo, const float* __restrict__ bo,
    const float* __restrict__ Ww, const float* __restrict__ bw,
    float* __restrict__ out) {
  const int p = blockIdx.x * blockDim.x + threadIdx.x;
  const int b = p / HW_;
  const int hw = p - b * HW_;
  const int y = hw / W_;
  const int x = hw - y * W_;
  const float* fb = feat + b * CHW_;
  float acc[24];
#pragma unroll
  for (int i = 0; i < 16; ++i) acc[i] = bo[i];
#pragma unroll
  for (int i = 0; i < 8; ++i) acc[16 + i] = bw[i];
#pragma unroll
  for (int c = 0; c < C_; ++c) {
    const float v = fb[c * HW_ + hw];
#pragma unroll
    for (int i = 0; i < 16; ++i) acc[i] = fmaf(Wo[i * C_ + c], v, acc[i]);
#pragma unroll
    for (int i = 0; i < 8; ++i) acc[16 + i] = fmaf(Ww[i * C_ + c], v, acc[16 + i]);
  }
  float m = acc[16];
#pragma unroll
  for (int k = 1; k < K_; ++k) m = fmaxf(m, acc[16 + k]);
  float wt[K_];
  float s = 0.f;
#pragma unroll
  for (int k = 0; k < K_; ++k) { wt[k] = __expf(acc[16 + k] - m); s += wt[k]; }
  const float fm = (mask[p] != 0) ? 1.f : 0.f;
  const float inv = fm / s;
#pragma unroll
  for (int k = 0; k < K_; ++k) wt[k] *= inv;
  float res[C_];
#pragma unroll
  for (int c = 0; c < C_; ++c) res[c] = 0.f;
  if (fm != 0.f) {
#pragma unroll
    for (int k = 0; k < K_; ++k) {
      const float px = (float)x + acc[2 * k];
      const float py = (float)y + acc[2 * k + 1];
      const float x0f = floorf(px), y0f = floorf(py);
      const float wx = px - x0f, wy = py - y0f;
      const int x0 = (int)x0f, y0 = (int)y0f;
      const int x1 = x0 + 1, y1 = y0 + 1;
      const bool vx0 = ((unsigned)x0 < (unsigned)W_);
      const bool vx1 = ((unsigned)x1 < (unsigned)W_);
      const bool vy0 = ((unsigned)y0 < (unsigned)H_);
      const bool vy1 = ((unsigned)y1 < (unsigned)H_);
      const int cx0 = min(max(x0, 0), W_ - 1), cx1 = min(max(x1, 0), W_ - 1);
      const int cy0 = min(max(y0, 0), H_ - 1), cy1 = min(max(y1, 0), H_ - 1);
      const float wk = wt[k];
      const float w00 = wk * (1.f - wx) * (1.f - wy) * ((vx0 && vy0) ? 1.f : 0.f);
      const float w01 = wk * wx * (1.f - wy) * ((vx1 && vy0) ? 1.f : 0.f);
      const float w10 = wk * (1.f - wx) * wy * ((vx0 && vy1) ? 1.f : 0.f);
      const float w11 = wk * wx * wy * ((vx1 && vy1) ? 1.f : 0.f);
      const int i00 = cy0 * W_ + cx0, i01 = cy0 * W_ + cx1;
      const int i10 = cy1 * W_ + cx0, i11 = cy1 * W_ + cx1;
#pragma unroll
      for (int c = 0; c < C_; ++c) {
        const float* fc = fb + c * HW_;
        res[c] += w00 * fc[i00] + w01 * fc[i01] + w10 * fc[i10] + w11 * fc[i11];
      }
    }
  }
#pragma unroll
  for (int c = 0; c < C_; ++c)
    out[b * CHW_ + c * HW_ + hw] = fb[c * HW_ + hw] + res[c];
}

extern "C" void kernel_launch(void* const* d_in, const int* in_sizes, int n_in,
                              void* d_out, int out_size, void* d_ws, size_t ws_size,
                              hipStream_t stream) {
  const float* feat = (const float*)d_in[0];
  const int* mask = (const int*)d_in[1];
  const float* Wo = (const float*)d_in[2];
  const float* bo = (const float*)d_in[3];
  const float* Ww = (const float*)d_in[4];
  const float* bw = (const float*)d_in[5];
  float* out = (float*)d_out;

  if (ws_size >= WS_NEED_) {
    unsigned short* ws = (unsigned short*)d_ws;
    hipLaunchKernelGGL(transposeh_kernel, dim3(NBLK_), dim3(256), 0, stream,
                       feat, ws);
    hipLaunchKernelGGL(fusedg_kernel, dim3(NBLK_), dim3(256), 0, stream,
                       feat, mask, Wo, bo, Ww, bw, ws, out);
  } else {
    hipLaunchKernelGGL(fused_kernel, dim3(NP_ / 256), dim3(256), 0, stream,
                       feat, mask, Wo, bo, Ww, bw, out);
  }
}